// Round 4
// baseline (239.868 us; speedup 1.0000x reference)
//
#include <hip/hip_runtime.h>
#include <hip/hip_bf16.h>

// Problem constants (fixed by setup_inputs)
constexpr int B = 4, Q = 100, C = 40, Cp1 = 41, HW = 65536;
constexpr int NPIX = B * HW;          // 262144
constexpr int CHUNKS = 4;             // kB blocks per (b,q)
constexpr int CPX = HW / CHUNKS;      // 16384 pixels per kB block

// Workspace layout (in 4-byte words)
//  [0, 16000)      counts  u32 [B][Q][C]
//  [16000, 16160)  tsum    u32 [B][C]
//  [16160, 32160)  inter   f32 [B][Q][C]
//  [32160, 32560)  src_sum f32 [B][Q]
//  [32560]         ce_sum  f32
//  [32561]         n_valid u32
constexpr int WS_WORDS = 32562;

__global__ void kZ(unsigned* __restrict__ ws, int n) {
    int i = blockIdx.x * blockDim.x + threadIdx.x;
    for (; i < n; i += gridDim.x * blockDim.x) ws[i] = 0u;
}

// Kernel A: pixel-major. Per pixel: argmax_q, online logsumexp over q, x[tgt].
// Produces counts[b][assign][tgt], tsum[b][tgt], ce_sum (sum of valid nll), n_valid.
__global__ __launch_bounds__(256) void kA(const float* __restrict__ masks,
                                          const int* __restrict__ targets,
                                          unsigned* __restrict__ counts,
                                          unsigned* __restrict__ tsum,
                                          float* __restrict__ ce_sum,
                                          unsigned* __restrict__ n_valid) {
    int tid = threadIdx.x;
    int pix = blockIdx.x * 256 + tid;          // block spans one b (65536 % 256 == 0)
    int b = pix >> 16;
    int hw = pix & 65535;
    const float* mp = masks + (size_t)b * Q * HW + hw;
    int tgt = targets[pix];

    float m = -INFINITY, s = 0.f, xt = 0.f;
    int amax = 0;
    #pragma unroll 4
    for (int q = 0; q < Q; ++q) {
        float v = mp[(size_t)q * HW];
        float nm = fmaxf(m, v);
        s = s * __expf(m - nm) + __expf(v - nm);   // branchless online lse
        amax = (v > m) ? q : amax;                  // strict > keeps first max (jnp.argmax)
        m = nm;
        xt = (q == tgt) ? v : xt;
    }

    __shared__ unsigned ts_local[C];
    __shared__ float cred[4];
    __shared__ unsigned vred[4];
    if (tid < C) ts_local[tid] = 0u;
    __syncthreads();

    float ce = 0.f;
    unsigned nv = 0;
    if (tgt != 255) {   // valid; tgt in [0,40)
        float lse = m + __logf(s);
        ce = lse - xt;
        nv = 1;
        atomicAdd(&counts[((size_t)b * Q + amax) * C + tgt], 1u);
        atomicAdd(&ts_local[tgt], 1u);
    }

    // wave reduce ce / nv
    for (int off = 32; off; off >>= 1) {
        ce += __shfl_xor(ce, off);
        nv += __shfl_xor(nv, off);
    }
    int lane = tid & 63, wave = tid >> 6;
    if (lane == 0) { cred[wave] = ce; vred[wave] = nv; }
    __syncthreads();   // also covers ts_local atomics
    if (tid == 0) {
        atomicAdd(ce_sum, cred[0] + cred[1] + cred[2] + cred[3]);
        atomicAdd(n_valid, vred[0] + vred[1] + vred[2] + vred[3]);
    }
    if (tid < C) {
        unsigned t = ts_local[tid];
        if (t) atomicAdd(&tsum[b * C + tid], t);
    }
}

// Kernel B: (b,q)-major. Per (b,q) chunk: sigmoid sums total (src_sum) and
// grouped-by-class (inter) via per-thread LDS histograms (conflict-free:
// thread t always hits bank t%32, 2 lanes/bank = free per m136).
// NOTE R1 bug fixed here: stride is it*1024 (256 thr * 4 px), NOT it*4096.
__global__ __launch_bounds__(256) void kB(const float* __restrict__ masks,
                                          const int* __restrict__ targets,
                                          float* __restrict__ inter,
                                          float* __restrict__ src_sum) {
    __shared__ float hist[C][256];   // 40 KB
    int tid = threadIdx.x;
    int bq = blockIdx.x >> 2;        // / CHUNKS
    int chunk = blockIdx.x & 3;
    int b = bq / Q;
    const float* mp = masks + (size_t)bq * HW + chunk * CPX;
    const int* tp = targets + (size_t)b * HW + chunk * CPX;

    #pragma unroll
    for (int c = 0; c < C; ++c) hist[c][tid] = 0.f;   // own column only

    float sacc = 0.f;
    for (int it = 0; it < CPX / 1024; ++it) {          // 16 iters * 1024 px = 16384
        int off = it * 1024 + tid * 4;                 // max 15*1024+1020+4 = 16384: in-bounds
        float4 x = *(const float4*)(mp + off);
        int4 tg = *(const int4*)(tp + off);
        float xs[4] = {x.x, x.y, x.z, x.w};
        int cs[4] = {tg.x, tg.y, tg.z, tg.w};
        #pragma unroll
        for (int j = 0; j < 4; ++j) {
            float sig = 1.f / (1.f + __expf(-xs[j]));
            sacc += sig;
            if ((unsigned)cs[j] < (unsigned)C) hist[cs[j]][tid] += sig;
        }
    }

    // src_sum: wave reduce + atomic
    for (int off = 32; off; off >>= 1) sacc += __shfl_xor(sacc, off);
    int lane = tid & 63, wave = tid >> 6;
    if (lane == 0) atomicAdd(&src_sum[bq], sacc);

    __syncthreads();
    // reduce hist columns: wave w handles 10 classes
    for (int c = wave * 10; c < wave * 10 + 10; ++c) {
        float h = hist[c][lane] + hist[c][lane + 64] + hist[c][lane + 128] + hist[c][lane + 192];
        for (int off = 32; off; off >>= 1) h += __shfl_xor(h, off);
        if (lane == 0) atomicAdd(&inter[(size_t)bq * C + c], h);
    }
}

// Kernel C: finalize. Single block. Output is f32 scalar.
__global__ __launch_bounds__(512) void kC(const float* __restrict__ logits,
                                          const unsigned* __restrict__ counts,
                                          const unsigned* __restrict__ tsum,
                                          const float* __restrict__ inter,
                                          const float* __restrict__ src_sum,
                                          const float* __restrict__ ce_sum,
                                          const unsigned* __restrict__ n_valid,
                                          float* __restrict__ out) {
    int tid = threadIdx.x;
    __shared__ float dice_sum[C];
    __shared__ float wred[8];
    __shared__ float s_lce;
    if (tid < C) dice_sum[tid] = 0.f;

    // ---- focal CE over (b,q) ----
    float ce_acc = 0.f;
    for (int i = tid; i < B * Q; i += 512) {
        const unsigned* cnt = counts + (size_t)i * C;
        unsigned best = 0;
        int tc = C;                       // stays C iff all counts zero (has_pix false)
        #pragma unroll
        for (int c = 0; c < C; ++c) {
            unsigned v = cnt[c];
            if (v > best) { best = v; tc = c; }   // strict >: ties -> smallest class
        }
        if (tc != C) {
            const float* lg = logits + (size_t)i * Cp1;
            float mm = -INFINITY, xt = 0.f;
            #pragma unroll
            for (int c = 0; c < Cp1; ++c) {
                float v = lg[c];
                mm = fmaxf(mm, v);
                if (c == tc) xt = v;
            }
            float ss = 0.f;
            #pragma unroll
            for (int c = 0; c < Cp1; ++c) ss += __expf(lg[c] - mm);
            float nll = mm + __logf(ss) - xt;  // empty_weight[tc]=1 for tc<C
            float p = __expf(-nll);
            float om = 1.f - p;
            ce_acc += om * om * nll;
        }
    }
    for (int off = 32; off; off >>= 1) ce_acc += __shfl_xor(ce_acc, off);
    if ((tid & 63) == 0) wred[tid >> 6] = ce_acc;
    __syncthreads();
    if (tid == 0) {
        float t = 0.f;
        for (int w = 0; w < 8; ++w) t += wred[w];
        s_lce = t;
    }

    // ---- dice over (b,q,c) ----
    for (int i = tid; i < B * Q * C; i += 512) {
        int bq = i / C, c = i - bq * C;
        float denom = src_sum[bq] + (float)tsum[(bq / Q) * C + c] + 1e-8f;
        atomicAdd(&dice_sum[c], 2.f * inter[i] / denom);
    }
    __syncthreads();

    if (tid == 0) {
        float dl = 0.f;
        for (int c = 0; c < C; ++c) {
            unsigned ts = tsum[c] + tsum[C + c] + tsum[2 * C + c] + tsum[3 * C + c];
            if (ts > 0) dl += 1.f - dice_sum[c] * (1.f / (B * Q));
        }
        dl *= (1.f / C);
        float ce_mask = ce_sum[0] / fmaxf((float)n_valid[0], 1.f);
        float lce = s_lce * (1.f / (B * Q));
        out[0] = 2.f * lce + 5.f * ce_mask + 5.f * dl;   // f32 scalar
    }
}

extern "C" void kernel_launch(void* const* d_in, const int* in_sizes, int n_in,
                              void* d_out, int out_size, void* d_ws, size_t ws_size,
                              hipStream_t stream) {
    const float* logits  = (const float*)d_in[0];   // [B,Q,41] f32
    const float* masks   = (const float*)d_in[1];   // [B,Q,H,W] f32
    const int*   targets = (const int*)d_in[2];     // [B,H,W] int32
    float* out = (float*)d_out;                     // f32 scalar

    unsigned* ws      = (unsigned*)d_ws;
    unsigned* counts  = ws;                         // 16000 u32
    unsigned* tsum    = ws + 16000;                 // 160 u32
    float*    inter   = (float*)(ws + 16160);       // 16000 f32
    float*    src_sum = (float*)(ws + 32160);       // 400 f32
    float*    ce_sum  = (float*)(ws + 32560);       // 1 f32
    unsigned* n_valid = ws + 32561;                 // 1 u32

    kZ<<<32, 256, 0, stream>>>(ws, WS_WORDS);
    kA<<<NPIX / 256, 256, 0, stream>>>(masks, targets, counts, tsum, ce_sum, n_valid);
    kB<<<B * Q * CHUNKS, 256, 0, stream>>>(masks, targets, inter, src_sum);
    kC<<<1, 512, 0, stream>>>(logits, counts, tsum, inter, src_sum, ce_sum, n_valid, out);
}